// Round 13
// baseline (37.646 us; speedup 1.0000x reference)
//
#include <hip/hip_runtime.h>

// SSIM loss, N=64 images, 1 ch, 384x384 f32, 7x7 box, VALID -> 378x378. out = -mean(S).
//
// R13 = R8 structure (28.45us best) with COLUMN-SPLIT occupancy doubling.
// Evidence: R5/R8/R10/R12 all run 1728 one-wave blocks = 1.69 waves/SIMD and
// sit ~75% stalled (VALUBusy ~24%) regardless of shuffle batching (R10),
// prefetch depth (R12), or dual-stream (R11 doubled BW but also bytes).
// The untested clean lever: 2x resident waves at IDENTICAL per-wave structure
// and ~same bytes. Each band is split into two 189-output-column stripes:
//   stripe 0: input cols 0..195   (lane l holds cols 4l..4l+3)
//   stripe 1: input cols 188..383 (lane l holds cols 188+4l..188+4l+3)
// CPL=4 -> LOADROW is one aligned dwordx4 per array. Lanes 49..63 idle
// (clamped in-bounds addresses; ownership check masks their outputs; their
// junk regs feed shuffles only into masked outputs -- verified at both
// boundaries). Grid 27 x 2 x 64 = 3456 waves = 3.4/SIMD at launch_bounds(64,3).
//  - 7-deep raw register history, statically indexed (7-step inner unroll)
//  - 2-deep new-row prefetch; rolled kk loop (I$); t34 merge
//  - two-kernel deterministic reduction

constexpr int IND    = 384;
constexpr int OUTD   = 378;
constexpr int RB     = 14;           // output rows per band
constexpr int BANDS  = OUTD / RB;    // 27
constexpr int CPL    = 4;            // cols per lane
constexpr int SW     = 189;          // output cols per stripe

using f32x4 = __attribute__((ext_vector_type(4))) float;

__global__ __launch_bounds__(64, 3)
void ssim_band(const float* __restrict__ X, const float* __restrict__ Y,
               const float* __restrict__ MX, float* __restrict__ blocksum)
{
    const int band   = blockIdx.x;
    const int stripe = blockIdx.y;
    const int n      = blockIdx.z;
    const int lane   = threadIdx.x;
    const int r0     = band * RB;                    // r0 <= 364

    const int c0  = (stripe == 0 ? 0 : 188) + lane * CPL;  // logical cols c0..c0+3
    int c0c = c0; if (c0c > IND - CPL) c0c = IND - CPL;    // clamped (junk lanes)
    const int olo = stripe * SW;                     // owned outputs [olo, olo+189)

    const float* __restrict__ Xp = X + (size_t)n * (IND * IND) + c0c;
    const float* __restrict__ Yp = Y + (size_t)n * (IND * IND) + c0c;

    float hx[7][CPL], hy[7][CPL];                    // raw 7-row history
    float sx[CPL]  = {}, sy[CPL]  = {};
    float sxx[CPL] = {}, syy[CPL] = {}, sxy[CPL] = {};

#define LOADROW(DX, DY, R) {                                                  \
    f32x4 _a = *(const f32x4*)(Xp + (size_t)(R) * IND);                       \
    f32x4 _b = *(const f32x4*)(Yp + (size_t)(R) * IND);                       \
    DX[0]=_a.x; DX[1]=_a.y; DX[2]=_a.z; DX[3]=_a.w;                           \
    DY[0]=_b.x; DY[1]=_b.y; DY[2]=_b.z; DY[3]=_b.w; }

    // ---- prologue: rows r0..r0+6 into history, prefetch r0+7, r0+8 ----
#pragma unroll
    for (int k = 0; k < 7; ++k) LOADROW(hx[k], hy[k], r0 + k)

    float pax[CPL], pay[CPL], pbx[CPL], pby[CPL];
    LOADROW(pax, pay, r0 + 7)
    LOADROW(pbx, pby, r0 + 8)

#pragma unroll
    for (int k = 0; k < 7; ++k)
#pragma unroll
        for (int c = 0; c < CPL; ++c) {
            float x = hx[k][c], y = hy[k][c];
            sx[c] += x;  sy[c] += y;
            sxx[c] = fmaf(x, x, sxx[c]);
            syy[c] = fmaf(y, y, syy[c]);
            sxy[c] = fmaf(x, y, sxy[c]);
        }

    const float m   = MX[n];
    const float c1  = (0.01f * m) * (0.01f * m);
    const float c2  = (0.03f * m) * (0.03f * m);
    const float k1  = 2401.0f * c1;      // 49^2 * C1
    const float k2  = 2401.0f * c2;
    const float cn  = 49.0f / 48.0f;
    const float cn2 = 2.0f * cn;

    // Horizontal 7-tap with CPL=4:
    //   O[0] = T + shfl1(p3);          O[1] = sf1 + shfl1(T);
    //   O[2] = sf2 + shfl1(T) + shfl2(S0);  O[3] = S3 + shfl1(T) + shfl2(p2);
    // where p2=S0+S1, p3=p2+S2, T=p3+S3, sf2=S2+S3, sf1=S1+sf2.
#define HSUM4(S, O) {                                                         \
    float _p2 = S[0] + S[1];                                                  \
    float _p3 = _p2 + S[2];                                                   \
    float _T  = _p3 + S[3];                                                   \
    float _n1p3 = __shfl_down(_p3, 1);                                        \
    float _n1T  = __shfl_down(_T, 1);                                         \
    float _n2p1 = __shfl_down(S[0], 2);                                       \
    float _n2p2 = __shfl_down(_p2, 2);                                        \
    float _sf2 = S[2] + S[3];                                                 \
    float _sf1 = S[1] + _sf2;                                                 \
    O[0] = _T   + _n1p3;                                                      \
    O[1] = _sf1 + _n1T;                                                       \
    O[2] = _sf2 + (_n1T + _n2p1);                                             \
    O[3] = S[3] + (_n1T + _n2p2); }

    float partial = 0.f;

    // Invariant at step s = 7kk+i: sums hold rows r0+s..r0+s+6 (slot i holds
    // row r0+s); pax = row r0+s+7, pbx = r0+s+8.
#pragma unroll 1                       // keep the 7-step body I$-resident
    for (int kk = 0; kk < RB / 7; ++kk) {
#pragma unroll
        for (int i = 0; i < 7; ++i) {
            // ---- 1. horizontal 7-tap window sums for output row r0+s ----
            float t1[CPL], t2[CPL], t34[CPL], t5[CPL], u[CPL];
            HSUM4(sx,  t1) HSUM4(sy,  t2) HSUM4(sxy, t5)
#pragma unroll
            for (int c = 0; c < CPL; ++c) u[c] = sxx[c] + syy[c];
            HSUM4(u, t34)

            // ---- 2. slide (-row s, +row s+7), rotate pipe, issue load ----
#pragma unroll
            for (int c = 0; c < CPL; ++c) {
                float nx = pax[c], ny = pay[c];
                float ox = hx[i][c], oy = hy[i][c];
                sx[c] += nx - ox;
                sy[c] += ny - oy;
                sxx[c] = fmaf(nx, nx, fmaf(-ox, ox, sxx[c]));
                syy[c] = fmaf(ny, ny, fmaf(-oy, oy, syy[c]));
                sxy[c] = fmaf(nx, ny, fmaf(-ox, oy, sxy[c]));
                hx[i][c] = nx;   hy[i][c] = ny;
                pax[c] = pbx[c]; pay[c] = pby[c];
            }
            {
                int nr = r0 + 7 * kk + i + 9;      // 2 rows ahead
                if (nr > IND - 1) nr = IND - 1;    // tail: clamped, never consumed
                LOADROW(pbx, pby, nr)
            }

            // ---- 3. SSIM formula (49^4-scaled, q-invariant), ownership mask ----
#pragma unroll
            for (int c = 0; c < CPL; ++c) {
                int o = c0 + c;                    // unclamped output col
                if (o >= olo && o < olo + SW && o < OUTD) {
                    float pxy = t1[c] * t2[c];
                    float ss  = fmaf(t1[c], t1[c], t2[c] * t2[c]);
                    float A1  = fmaf(2.f, pxy, k1);
                    float B1  = ss + k1;
                    float A2  = fmaf(cn2, fmaf(49.f, t5[c], -pxy), k2);
                    float B2  = fmaf(cn, fmaf(49.f, t34[c], -ss), k2);
                    partial += __fdividef(A1 * A2, B1 * B2);
                }
            }
        }
    }
#undef HSUM4
#undef LOADROW

    // ---- wave reduction (deterministic) ----
#pragma unroll
    for (int off = 32; off; off >>= 1) partial += __shfl_down(partial, off);
    if (lane == 0)
        blocksum[((size_t)n * 2 + stripe) * BANDS + band] = partial;
}

__global__ __launch_bounds__(256)
void ssim_reduce(const float* __restrict__ blocksum, float* __restrict__ out,
                 int nblocks, float inv_npix)
{
    const int tid = threadIdx.x;
    float s = 0.f;
    for (int i = tid; i < nblocks; i += 256) s += blocksum[i];
#pragma unroll
    for (int off = 32; off; off >>= 1) s += __shfl_down(s, off);
    __shared__ float ws[4];
    if ((tid & 63) == 0) ws[tid >> 6] = s;
    __syncthreads();
    if (tid == 0) out[0] = -(ws[0] + ws[1] + ws[2] + ws[3]) * inv_npix;
}

extern "C" void kernel_launch(void* const* d_in, const int* in_sizes, int n_in,
                              void* d_out, int out_size, void* d_ws, size_t ws_size,
                              hipStream_t stream)
{
    const float* X  = (const float*)d_in[0];
    const float* Y  = (const float*)d_in[1];
    // d_in[2] = norm (unused by reference), d_in[4] = w (ones/49, baked in)
    const float* MX = (const float*)d_in[3];

    const int N       = in_sizes[3];             // 64
    const int nblocks = N * 2 * BANDS;           // 3456

    float* bs = (float*)d_ws;

    dim3 grid(BANDS, 2, N);
    ssim_band<<<grid, 64, 0, stream>>>(X, Y, MX, bs);

    const float inv_npix = 1.0f / ((float)N * OUTD * OUTD);
    ssim_reduce<<<1, 256, 0, stream>>>(bs, (float*)d_out, nblocks, inv_npix);
}

// Round 14
// 28.507 us; speedup vs baseline: 1.3206x; 1.3206x over previous
//
#include <hip/hip_runtime.h>

// SSIM loss, N=64 images, 1 ch, 384x384 f32, 7x7 box, VALID -> 378x378. out = -mean(S).
//
// R14 = R8 body VERBATIM, repackaged: 4 independent band-waves per 256-thread
// block (was 1 wave per 64-thread block).
// Evidence: all rounds' time ~ inst-count / fixed ~24% issue efficiency; the
// only kernels ever exceeding 40% VALUBusy were 256-thr blocks (R2/R3, 3.1
// waves/SIMD resident). Single-wave blocks never achieve residency: R11
// OccupancyPercent 12.97% = 1.04 waves/SIMD resident vs 1.69 supplied by the
// grid; R6 23.8% = 1.9 vs 3.38 supplied. The dispatcher does not stack tiny
// blocks; multi-wave blocks it does. R14 changes ONLY the packaging: same
// per-wave instructions, same bytes, no barriers (waves fully independent,
// per-wave shuffle reduction, each wave writes its own blocksum slot).
//  - wave w of block g owns band 4g+w (guard band<27; idle wave exits early)
//  - lane owns cols 6l..6l+5 (64*6=384), RB=14, 7-deep register history,
//    2-deep prefetch, rolled kk loop, t34 merge, two-kernel reduction

constexpr int IND   = 384;
constexpr int OUTD  = 378;
constexpr int RB    = 14;            // output rows per band
constexpr int BANDS = OUTD / RB;     // 27
constexpr int CPL   = 6;             // cols per lane
constexpr int WPB   = 4;             // waves per block
constexpr int GRPS  = (BANDS + WPB - 1) / WPB;   // 7 block-groups

using f32x2 = __attribute__((ext_vector_type(2))) float;

__global__ __launch_bounds__(256, 2)
void ssim_band(const float* __restrict__ X, const float* __restrict__ Y,
               const float* __restrict__ MX, float* __restrict__ blocksum)
{
    const int n    = blockIdx.y;
    const int wid  = threadIdx.x >> 6;
    const int lane = threadIdx.x & 63;
    const int band = blockIdx.x * WPB + wid;
    if (band >= BANDS) return;                 // no barriers in kernel: safe

    const int c0 = lane * CPL;
    const int r0 = band * RB;                  // input rows r0..r0+19 <= 383

    const float* __restrict__ Xp = X + (size_t)n * (IND * IND) + c0;
    const float* __restrict__ Yp = Y + (size_t)n * (IND * IND) + c0;

    float hx[7][CPL], hy[7][CPL];              // raw 7-row history
    float sx[CPL]  = {}, sy[CPL]  = {};
    float sxx[CPL] = {}, syy[CPL] = {}, sxy[CPL] = {};

#define LOADROW(DX, DY, R) {                                                  \
    const float* _px = Xp + (size_t)(R) * IND;                                \
    const float* _py = Yp + (size_t)(R) * IND;                                \
    f32x2 _a = *(const f32x2*)_px;                                            \
    f32x2 _b = *(const f32x2*)(_px + 2);                                      \
    f32x2 _c = *(const f32x2*)(_px + 4);                                      \
    f32x2 _d = *(const f32x2*)_py;                                            \
    f32x2 _e = *(const f32x2*)(_py + 2);                                      \
    f32x2 _f = *(const f32x2*)(_py + 4);                                      \
    DX[0]=_a.x; DX[1]=_a.y; DX[2]=_b.x; DX[3]=_b.y; DX[4]=_c.x; DX[5]=_c.y;   \
    DY[0]=_d.x; DY[1]=_d.y; DY[2]=_e.x; DY[3]=_e.y; DY[4]=_f.x; DY[5]=_f.y; }

    // ---- prologue: rows r0..r0+6 into history, prefetch r0+7, r0+8 ----
#pragma unroll
    for (int k = 0; k < 7; ++k) LOADROW(hx[k], hy[k], r0 + k)

    float pax[CPL], pay[CPL], pbx[CPL], pby[CPL];
    LOADROW(pax, pay, r0 + 7)
    LOADROW(pbx, pby, r0 + 8)

#pragma unroll
    for (int k = 0; k < 7; ++k)
#pragma unroll
        for (int c = 0; c < CPL; ++c) {
            float x = hx[k][c], y = hy[k][c];
            sx[c] += x;  sy[c] += y;
            sxx[c] = fmaf(x, x, sxx[c]);
            syy[c] = fmaf(y, y, syy[c]);
            sxy[c] = fmaf(x, y, sxy[c]);
        }

    const float m   = MX[n];
    const float c1  = (0.01f * m) * (0.01f * m);
    const float c2  = (0.03f * m) * (0.03f * m);
    const float k1  = 2401.0f * c1;      // 49^2 * C1
    const float k2  = 2401.0f * c2;
    const float cn  = 49.0f / 48.0f;
    const float cn2 = 2.0f * cn;

    // horizontal sliding sum: O[i] = sum over window cols (6l+i .. 6l+i+6)
#define HSUM(S, O) {                                                          \
    float _n0 = __shfl_down(S[0], 1), _n1 = __shfl_down(S[1], 1);             \
    float _n2 = __shfl_down(S[2], 1), _n3 = __shfl_down(S[3], 1);             \
    float _n4 = __shfl_down(S[4], 1), _n5 = __shfl_down(S[5], 1);             \
    float _t  = ((S[0]+S[1]) + (S[2]+S[3])) + (S[4]+S[5]);                    \
    O[0] = _t   + _n0;                                                        \
    O[1] = O[0] - S[0] + _n1;                                                 \
    O[2] = O[1] - S[1] + _n2;                                                 \
    O[3] = O[2] - S[2] + _n3;                                                 \
    O[4] = O[3] - S[3] + _n4;                                                 \
    O[5] = O[4] - S[4] + _n5; }

    float partial = 0.f;

#pragma unroll 1                       // keep the 7-step body I$-resident
    for (int kk = 0; kk < RB / 7; ++kk) {
#pragma unroll
        for (int i = 0; i < 7; ++i) {
            // ---- horizontal sums + formula for output row r0 + 7*kk + i ----
            float t1[CPL], t2[CPL], t34[CPL], t5[CPL], u[CPL];
            HSUM(sx,  t1) HSUM(sy,  t2) HSUM(sxy, t5)
#pragma unroll
            for (int c = 0; c < CPL; ++c) u[c] = sxx[c] + syy[c];
            HSUM(u, t34)

            if (lane < 63) {
#pragma unroll
                for (int c = 0; c < CPL; ++c) {
                    float pxy = t1[c] * t2[c];
                    float ss  = fmaf(t1[c], t1[c], t2[c] * t2[c]);
                    float A1  = fmaf(2.f, pxy, k1);
                    float B1  = ss + k1;
                    float A2  = fmaf(cn2, fmaf(49.f, t5[c], -pxy), k2);
                    float B2  = fmaf(cn, fmaf(49.f, t34[c], -ss), k2);
                    partial += __fdividef(A1 * A2, B1 * B2);
                }
            }

            // ---- slide: -row(r0+7kk+i) +row(r0+7kk+i+7); refill pipeline ----
#pragma unroll
            for (int c = 0; c < CPL; ++c) {
                float nx = pax[c], ny = pay[c];
                float ox = hx[i][c], oy = hy[i][c];
                sx[c] += nx - ox;
                sy[c] += ny - oy;
                sxx[c] = fmaf(nx, nx, fmaf(-ox, ox, sxx[c]));
                syy[c] = fmaf(ny, ny, fmaf(-oy, oy, syy[c]));
                sxy[c] = fmaf(nx, ny, fmaf(-ox, oy, sxy[c]));
                hx[i][c] = nx;  hy[i][c] = ny;
                pax[c] = pbx[c]; pay[c] = pby[c];
            }
            int nr = r0 + 7 * kk + i + 9;          // 2 rows ahead
            if (nr > IND - 1) nr = IND - 1;        // tail: harmless clamped load
            LOADROW(pbx, pby, nr)
        }
    }
#undef HSUM
#undef LOADROW

    // ---- per-wave reduction (deterministic; no cross-wave interaction) ----
#pragma unroll
    for (int off = 32; off; off >>= 1) partial += __shfl_down(partial, off);
    if (lane == 0) blocksum[(size_t)n * BANDS + band] = partial;
}

__global__ __launch_bounds__(256)
void ssim_reduce(const float* __restrict__ blocksum, float* __restrict__ out,
                 int nblocks, float inv_npix)
{
    const int tid = threadIdx.x;
    float s = 0.f;
    for (int i = tid; i < nblocks; i += 256) s += blocksum[i];
#pragma unroll
    for (int off = 32; off; off >>= 1) s += __shfl_down(s, off);
    __shared__ float ws[4];
    if ((tid & 63) == 0) ws[tid >> 6] = s;
    __syncthreads();
    if (tid == 0) out[0] = -(ws[0] + ws[1] + ws[2] + ws[3]) * inv_npix;
}

extern "C" void kernel_launch(void* const* d_in, const int* in_sizes, int n_in,
                              void* d_out, int out_size, void* d_ws, size_t ws_size,
                              hipStream_t stream)
{
    const float* X  = (const float*)d_in[0];
    const float* Y  = (const float*)d_in[1];
    // d_in[2] = norm (unused by reference), d_in[4] = w (ones/49, baked in)
    const float* MX = (const float*)d_in[3];

    const int N       = in_sizes[3];             // 64
    const int nblocks = N * BANDS;               // 1728 band sums

    float* bs = (float*)d_ws;

    dim3 grid(GRPS, N);                          // 7 x 64 blocks of 256 thr
    ssim_band<<<grid, 256, 0, stream>>>(X, Y, MX, bs);

    const float inv_npix = 1.0f / ((float)N * OUTD * OUTD);
    ssim_reduce<<<1, 256, 0, stream>>>(bs, (float*)d_out, nblocks, inv_npix);
}